// Round 1
// baseline (4195.247 us; speedup 1.0000x reference)
//
#include <hip/hip_runtime.h>
#include <math.h>

#define N_TOKENS 16384
#define DIM 2048
#define HID 4096
#define NEXP 8
#define TOPK 2
#define RCAP 33792      // 264 tiles * 128 rows (max padded rows)
#define MAXTILES 264

// meta layout (int indices into ws[0..4096))
#define MI_CNT 0        // int[8]  expert counts
#define MI_FILL 8       // int[8]  scatter fill counters
#define MI_USAGE 16     // float[8] usage sums (softmax prob sums)
#define MI_NTILES 24    // int     number of 128-row tiles
#define MI_EXPOFF 32    // int[9]  padded expert row offsets
#define MI_TILEEXP 64   // int[264] tile -> expert
#define MI_TILEROW 384  // int[264] tile -> padded row base

// ws byte offsets
#define WS_TOKE 4096
#define WS_TOKW (WS_TOKE + 131072)
#define WS_GTOK (WS_TOKW + 131072)
#define WS_GW   (WS_GTOK + 135168)
#define WS_H    1048576
#define WS_NEED (WS_H + (size_t)RCAP * HID * 2)            // old path: ~278 MB
#define WS_XB   WS_NEED                                     // bf16 x: 67 MB
#define WS_WT   (WS_XB + (size_t)N_TOKENS * DIM * 2)        // bf16 W^T (shared W1/W2): 134 MB
#define WS_NEED2 (WS_WT + (size_t)NEXP * DIM * HID * 2)     // ~457 MiB total

typedef __attribute__((ext_vector_type(8))) short short8;
typedef __attribute__((ext_vector_type(8))) unsigned short ushort8;
typedef __attribute__((ext_vector_type(4))) float floatx4;
typedef __attribute__((ext_vector_type(2))) unsigned int uintx2;

static __device__ __forceinline__ unsigned short f2bf(float f) {
  unsigned int u = __float_as_uint(f);
  u += 0x7fffu + ((u >> 16) & 1u);   // round-to-nearest-even
  return (unsigned short)(u >> 16);
}
static __device__ __forceinline__ unsigned int pack2(float a, float b) {
  return (unsigned int)f2bf(a) | ((unsigned int)f2bf(b) << 16);
}

// async global->LDS, 16B per lane, LDS dest = wave-uniform base + lane*16
static __device__ __forceinline__ void gload16(const void* g, void* l) {
  __builtin_amdgcn_global_load_lds(
      (__attribute__((address_space(1))) void*)(void*)g,
      (__attribute__((address_space(3))) void*)l, 16, 0, 0);
}

// ---------------- router: 1 wave per token, fp64 logits; also emits bf16 x ----------------
__global__ __launch_bounds__(256) void router_kernel(
    const float* __restrict__ x, const float* __restrict__ Wr,
    int* __restrict__ meta, int* __restrict__ tokE, float* __restrict__ tokW,
    unsigned short* __restrict__ xb) {
  int wv = threadIdx.x >> 6, lane = threadIdx.x & 63;
  int t = blockIdx.x * 4 + wv;
  const float4* xr = (const float4*)(x + (size_t)t * DIM);
  double acc[8];
#pragma unroll
  for (int e = 0; e < 8; ++e) acc[e] = 0.0;
#pragma unroll
  for (int i = 0; i < 8; ++i) {
    int d4 = i * 64 + lane;               // float4 index in [0,512)
    float4 xv = xr[d4];
    if (xb) {
      uintx2 p = {pack2(xv.x, xv.y), pack2(xv.z, xv.w)};
      *(uintx2*)(xb + (size_t)t * DIM + d4 * 4) = p;
    }
    const float* wr = Wr + (size_t)d4 * 32;  // 4 rows of 8 floats
    float xs[4] = {xv.x, xv.y, xv.z, xv.w};
#pragma unroll
    for (int j = 0; j < 4; ++j) {
      float4 w0 = *(const float4*)(wr + j * 8);
      float4 w1 = *(const float4*)(wr + j * 8 + 4);
      double xd = (double)xs[j];
      acc[0] += xd * (double)w0.x; acc[1] += xd * (double)w0.y;
      acc[2] += xd * (double)w0.z; acc[3] += xd * (double)w0.w;
      acc[4] += xd * (double)w1.x; acc[5] += xd * (double)w1.y;
      acc[6] += xd * (double)w1.z; acc[7] += xd * (double)w1.w;
    }
  }
#pragma unroll
  for (int off = 32; off > 0; off >>= 1) {
#pragma unroll
    for (int e = 0; e < 8; ++e) acc[e] += __shfl_down(acc[e], off);
  }
  if (lane == 0) {
    double m = acc[0];
#pragma unroll
    for (int e = 1; e < 8; ++e) m = acc[e] > m ? acc[e] : m;
    double p[8], s = 0.0;
#pragma unroll
    for (int e = 0; e < 8; ++e) { p[e] = exp(acc[e] - m); s += p[e]; }
    float* usage = (float*)(meta + MI_USAGE);
#pragma unroll
    for (int e = 0; e < 8; ++e) atomicAdd(usage + e, (float)(p[e] / s));
    int i0 = 0; double b0 = p[0];
#pragma unroll
    for (int e = 1; e < 8; ++e) if (p[e] > b0) { b0 = p[e]; i0 = e; }
    int i1 = -1; double b1v = -1.0;
#pragma unroll
    for (int e = 0; e < 8; ++e) if (e != i0 && p[e] > b1v) { b1v = p[e]; i1 = e; }
    double den = p[i0] + p[i1];
    tokE[2 * t] = i0; tokE[2 * t + 1] = i1;
    tokW[2 * t] = (float)(p[i0] / den); tokW[2 * t + 1] = (float)(p[i1] / den);
    atomicAdd(&meta[MI_CNT + i0], 1);
    atomicAdd(&meta[MI_CNT + i1], 1);
  }
}

// ---------------- offsets + tile map + loss (init moved to memset) ----------------
__global__ __launch_bounds__(64) void offsets_kernel(
    int* __restrict__ meta, float* __restrict__ out) {
  if (threadIdx.x == 0) {
    int off = 0, nt = 0;
    for (int e = 0; e < NEXP; ++e) {
      meta[MI_EXPOFF + e] = off;
      int c = meta[MI_CNT + e];
      int ntile = (c + 127) >> 7;
      for (int i = 0; i < ntile; ++i) {
        meta[MI_TILEEXP + nt] = e;
        meta[MI_TILEROW + nt] = off + i * 128;
        ++nt;
      }
      off += ntile * 128;
    }
    meta[MI_NTILES] = nt;
    float* usage = (float*)(meta + MI_USAGE);
    double loss = 0.0;
    for (int e = 0; e < NEXP; ++e)
      loss += ((double)usage[e] / N_TOKENS) *
              ((double)meta[MI_CNT + e] / (double)(N_TOKENS * TOPK));
    out[(size_t)N_TOKENS * DIM] = (float)(NEXP * loss);
  }
}

// ---------------- scatter tokens into expert-grouped rows ----------------
__global__ __launch_bounds__(256) void scatter_kernel(
    int* __restrict__ meta, const int* __restrict__ tokE,
    const float* __restrict__ tokW, int* __restrict__ gtok,
    float* __restrict__ gw) {
  int t = blockIdx.x * 256 + threadIdx.x;
  int e0 = tokE[2 * t], e1 = tokE[2 * t + 1];
  float w0 = tokW[2 * t], w1 = tokW[2 * t + 1];
  int p0 = atomicAdd(&meta[MI_FILL + e0], 1);
  int idx0 = meta[MI_EXPOFF + e0] + p0;
  gtok[idx0] = t; gw[idx0] = w0;
  int p1 = atomicAdd(&meta[MI_FILL + e1], 1);
  int idx1 = meta[MI_EXPOFF + e1] + p1;
  gtok[idx1] = t; gw[idx1] = w1;
}

// ---------------- weight convert+transpose: W[e][K][N] fp32 -> WT[e][N][K] bf16 ----------------
__global__ __launch_bounds__(256) void convw_kernel(
    const float* __restrict__ W, unsigned short* __restrict__ WT, int K, int N) {
  int e = blockIdx.z;
  int nBase = blockIdx.x * 64, kBase = blockIdx.y * 64;
  __shared__ __align__(16) unsigned short ldsT[64][72];  // [n][k], pad 8
  int tid = threadIdx.x;
  const float* Wp = W + (size_t)e * K * N;
#pragma unroll
  for (int it = 0; it < 4; ++it) {
    int k = it * 16 + (tid >> 4);
    int n4 = (tid & 15) * 4;
    float4 v = *(const float4*)(Wp + (size_t)(kBase + k) * N + nBase + n4);
    ldsT[n4 + 0][k] = f2bf(v.x);
    ldsT[n4 + 1][k] = f2bf(v.y);
    ldsT[n4 + 2][k] = f2bf(v.z);
    ldsT[n4 + 3][k] = f2bf(v.w);
  }
  __syncthreads();
  unsigned short* WTp = WT + (size_t)e * N * K;
#pragma unroll
  for (int it = 0; it < 2; ++it) {
    int n = it * 32 + (tid >> 3);
    int sg = tid & 7;
    ushort8 u = *(const ushort8*)&ldsT[n][sg * 8];
    *(ushort8*)(WTp + (size_t)(nBase + n) * K + kBase + sg * 8) = u;
  }
}

// ================= NEW bf16 GEMMs: 128x128 tile, BK=64, global_load_lds + XOR swizzle =================
// LDS layout: [128 rows][64 bf16] = 128B/row; physical chunk s holds logical chunk s^(row&7)
// (source pre-swizzled so gload_lds linear dest lands swizzled; ds_read applies same XOR).

__global__ __launch_bounds__(256, 2) void gemm1b_kernel(
    const unsigned short* __restrict__ xb, const unsigned short* __restrict__ w1t,
    const float* __restrict__ b1, const int* __restrict__ meta,
    const int* __restrict__ gtok, unsigned short* __restrict__ h) {
  int tileId = blockIdx.x;                 // tile-major dispatch: B panel stays L2-hot
  if (tileId >= meta[MI_NTILES]) return;
  int e = meta[MI_TILEEXP + tileId];
  int rowBase = meta[MI_TILEROW + tileId];
  int colBase = blockIdx.y * 128;
  const float* b1p = b1 + (size_t)e * HID;

  __shared__ __align__(16) unsigned short As[128 * 64];
  __shared__ __align__(16) unsigned short Bs[128 * 64];

  int tid = threadIdx.x;
  int s = tid & 7, rsub = tid >> 3;        // row-sub in [0,32), 8 lanes x 16B per row
  int sx = ((s ^ (rsub & 7)) * 8);         // swizzled element offset within 64-elem row

  const unsigned short* aSrc[4];
  const unsigned short* bSrc[4];
#pragma unroll
  for (int c = 0; c < 4; ++c) {
    int r = c * 32 + rsub;
    int tok = gtok[rowBase + r]; if (tok < 0) tok = 0;   // pad rows: garbage ok, discarded later
    aSrc[c] = xb + (size_t)tok * DIM + sx;
    bSrc[c] = w1t + ((size_t)e * HID + colBase + r) * DIM + sx;
  }
  int lane = tid & 63, wv = tid >> 6;
  int wm = wv & 1, wn = wv >> 1;
  int l15 = lane & 15, quad = lane >> 4;
  unsigned short* aLds[4];
  unsigned short* bLds[4];
#pragma unroll
  for (int c = 0; c < 4; ++c) {
    aLds[c] = As + (c * 32 + wv * 8) * 64;
    bLds[c] = Bs + (c * 32 + wv * 8) * 64;
  }

  floatx4 acc[4][4];
#pragma unroll
  for (int i = 0; i < 4; ++i)
#pragma unroll
    for (int j = 0; j < 4; ++j) acc[i][j] = (floatx4){0.f, 0.f, 0.f, 0.f};

  for (int kc = 0; kc < DIM / 64; ++kc) {
#pragma unroll
    for (int c = 0; c < 4; ++c) gload16(aSrc[c] + kc * 64, aLds[c]);
#pragma unroll
    for (int c = 0; c < 4; ++c) gload16(bSrc[c] + kc * 64, bLds[c]);
    __syncthreads();
#pragma unroll
    for (int ks = 0; ks < 2; ++ks) {
      short8 af[4], bfr[4];
#pragma unroll
      for (int i = 0; i < 4; ++i) {
        int R = wm * 64 + i * 16 + l15;
        int off = R * 128 + (((ks << 6) | (quad << 4)) ^ ((R & 7) << 4));
        af[i] = *(const short8*)((const char*)As + off);
      }
#pragma unroll
      for (int j = 0; j < 4; ++j) {
        int R = wn * 64 + j * 16 + l15;
        int off = R * 128 + (((ks << 6) | (quad << 4)) ^ ((R & 7) << 4));
        bfr[j] = *(const short8*)((const char*)Bs + off);
      }
#pragma unroll
      for (int i = 0; i < 4; ++i)
#pragma unroll
        for (int j = 0; j < 4; ++j)
          acc[i][j] = __builtin_amdgcn_mfma_f32_16x16x32_bf16(af[i], bfr[j], acc[i][j], 0, 0, 0);
    }
    __syncthreads();
  }

#pragma unroll
  for (int j = 0; j < 4; ++j) {
    int col = colBase + wn * 64 + j * 16 + l15;
    float bb = b1p[col];
#pragma unroll
    for (int i = 0; i < 4; ++i) {
#pragma unroll
      for (int r = 0; r < 4; ++r) {
        int lrow = wm * 64 + i * 16 + quad * 4 + r;
        float v = acc[i][j][r] + bb;
        v = 0.5f * v * (1.0f + erff(v * 0.70710678118654752f));
        h[(size_t)(rowBase + lrow) * HID + col] = f2bf(v);
      }
    }
  }
}

__global__ __launch_bounds__(256, 2) void gemm2b_kernel(
    const unsigned short* __restrict__ h, const unsigned short* __restrict__ w2t,
    const float* __restrict__ b2, const int* __restrict__ meta,
    const int* __restrict__ gtok, const float* __restrict__ gw,
    float* __restrict__ out) {
  int tileId = blockIdx.x;
  if (tileId >= meta[MI_NTILES]) return;
  int e = meta[MI_TILEEXP + tileId];
  int rowBase = meta[MI_TILEROW + tileId];
  int colBase = blockIdx.y * 128;
  const float* b2p = b2 + (size_t)e * DIM;

  __shared__ __align__(16) unsigned short As[128 * 64];
  __shared__ __align__(16) unsigned short Bs[128 * 64];

  int tid = threadIdx.x;
  int s = tid & 7, rsub = tid >> 3;
  int sx = ((s ^ (rsub & 7)) * 8);

  const unsigned short* aSrc[4];
  const unsigned short* bSrc[4];
#pragma unroll
  for (int c = 0; c < 4; ++c) {
    int r = c * 32 + rsub;
    aSrc[c] = h + (size_t)(rowBase + r) * HID + sx;
    bSrc[c] = w2t + ((size_t)e * DIM + colBase + r) * HID + sx;
  }
  int lane = tid & 63, wv = tid >> 6;
  int wm = wv & 1, wn = wv >> 1;
  int l15 = lane & 15, quad = lane >> 4;
  unsigned short* aLds[4];
  unsigned short* bLds[4];
#pragma unroll
  for (int c = 0; c < 4; ++c) {
    aLds[c] = As + (c * 32 + wv * 8) * 64;
    bLds[c] = Bs + (c * 32 + wv * 8) * 64;
  }

  floatx4 acc[4][4];
#pragma unroll
  for (int i = 0; i < 4; ++i)
#pragma unroll
    for (int j = 0; j < 4; ++j) acc[i][j] = (floatx4){0.f, 0.f, 0.f, 0.f};

  for (int kc = 0; kc < HID / 64; ++kc) {
#pragma unroll
    for (int c = 0; c < 4; ++c) gload16(aSrc[c] + kc * 64, aLds[c]);
#pragma unroll
    for (int c = 0; c < 4; ++c) gload16(bSrc[c] + kc * 64, bLds[c]);
    __syncthreads();
#pragma unroll
    for (int ks = 0; ks < 2; ++ks) {
      short8 af[4], bfr[4];
#pragma unroll
      for (int i = 0; i < 4; ++i) {
        int R = wm * 64 + i * 16 + l15;
        int off = R * 128 + (((ks << 6) | (quad << 4)) ^ ((R & 7) << 4));
        af[i] = *(const short8*)((const char*)As + off);
      }
#pragma unroll
      for (int j = 0; j < 4; ++j) {
        int R = wn * 64 + j * 16 + l15;
        int off = R * 128 + (((ks << 6) | (quad << 4)) ^ ((R & 7) << 4));
        bfr[j] = *(const short8*)((const char*)Bs + off);
      }
#pragma unroll
      for (int i = 0; i < 4; ++i)
#pragma unroll
        for (int j = 0; j < 4; ++j)
          acc[i][j] = __builtin_amdgcn_mfma_f32_16x16x32_bf16(af[i], bfr[j], acc[i][j], 0, 0, 0);
    }
    __syncthreads();
  }

  int toks[16]; float wts[16];
#pragma unroll
  for (int i = 0; i < 4; ++i)
#pragma unroll
    for (int r = 0; r < 4; ++r) {
      int grow = rowBase + wm * 64 + i * 16 + quad * 4 + r;
      toks[i * 4 + r] = gtok[grow];
      wts[i * 4 + r] = gw[grow];
    }
#pragma unroll
  for (int j = 0; j < 4; ++j) {
    int col = colBase + wn * 64 + j * 16 + l15;
    float bb = b2p[col];
#pragma unroll
    for (int i = 0; i < 4; ++i) {
#pragma unroll
      for (int r = 0; r < 4; ++r) {
        int tokr = toks[i * 4 + r];
        if (tokr >= 0)
          atomicAdd(out + (size_t)tokr * DIM + col, wts[i * 4 + r] * (acc[i][j][r] + bb));
      }
    }
  }
}

// ================= OLD fp32-operand GEMMs (fallback when ws is small) =================
__global__ __launch_bounds__(256, 2) void gemm1_kernel(
    const float* __restrict__ x, const float* __restrict__ W1,
    const float* __restrict__ b1, const int* __restrict__ meta,
    const int* __restrict__ gtok, unsigned short* __restrict__ h) {
  int tileId = blockIdx.y;
  if (tileId >= meta[MI_NTILES]) return;
  int e = meta[MI_TILEEXP + tileId];
  int rowBase = meta[MI_TILEROW + tileId];
  int colBase = blockIdx.x * 128;
  const float* Bp = W1 + (size_t)e * DIM * HID + colBase;
  const float* b1p = b1 + (size_t)e * HID;

  __shared__ __align__(16) unsigned short As[128 * 32];
  __shared__ __align__(16) unsigned short Bs[128 * 32];

  int tid = threadIdx.x;
  int arow = tid >> 1, aseg = (tid & 1) * 16;
  int tok = gtok[rowBase + arow];
  const float* ap = x + (size_t)(tok >= 0 ? tok : 0) * DIM + aseg;
  int bk = (tid & 15) * 2;
  int bn = (tid >> 4) * 8;
  const float* bp = Bp + (size_t)bk * HID + bn;

  int lane = tid & 63, wv = tid >> 6;
  int wm = wv & 1, wn = wv >> 1;
  int l15 = lane & 15, quad = lane >> 4;

  floatx4 acc[4][4];
#pragma unroll
  for (int i = 0; i < 4; ++i)
#pragma unroll
    for (int j = 0; j < 4; ++j) acc[i][j] = (floatx4){0.f, 0.f, 0.f, 0.f};

  for (int kc = 0; kc < DIM / 32; ++kc) {
    float4 a0, a1, a2, a3;
    if (tok >= 0) {
      const float4* av = (const float4*)(ap + kc * 32);
      a0 = av[0]; a1 = av[1]; a2 = av[2]; a3 = av[3];
    } else {
      a0 = a1 = a2 = a3 = (float4){0.f, 0.f, 0.f, 0.f};
    }
    const float* bpk = bp + (size_t)kc * 32 * HID;
    float4 r00 = ((const float4*)bpk)[0], r01 = ((const float4*)bpk)[1];
    float4 r10 = ((const float4*)(bpk + HID))[0], r11 = ((const float4*)(bpk + HID))[1];

    uint4 pa0 = {pack2(a0.x, a0.y), pack2(a0.z, a0.w), pack2(a1.x, a1.y), pack2(a1.z, a1.w)};
    uint4 pa1 = {pack2(a2.x, a2.y), pack2(a2.z, a2.w), pack2(a3.x, a3.y), pack2(a3.z, a3.w)};
    *(uint4*)&As[arow * 32 + aseg] = pa0;
    *(uint4*)&As[arow * 32 + aseg + 8] = pa1;

    unsigned int pr[8] = {pack2(r00.x, r10.x), pack2(r00.y, r10.y),
                          pack2(r00.z, r10.z), pack2(r00.w, r10.w),
                          pack2(r01.x, r11.x), pack2(r01.y, r11.y),
                          pack2(r01.z, r11.z), pack2(r01.w, r11.w)};
#pragma unroll
    for (int j = 0; j < 8; ++j)
      *(unsigned int*)&Bs[(bn + j) * 32 + bk] = pr[j];
    __syncthreads();

    short8 af[4], bfr[4];
#pragma unroll
    for (int i = 0; i < 4; ++i)
      af[i] = *(const short8*)&As[(wm * 64 + i * 16 + l15) * 32 + quad * 8];
#pragma unroll
    for (int j = 0; j < 4; ++j)
      bfr[j] = *(const short8*)&Bs[(wn * 64 + j * 16 + l15) * 32 + quad * 8];
#pragma unroll
    for (int i = 0; i < 4; ++i)
#pragma unroll
      for (int j = 0; j < 4; ++j)
        acc[i][j] = __builtin_amdgcn_mfma_f32_16x16x32_bf16(af[i], bfr[j], acc[i][j], 0, 0, 0);
    __syncthreads();
  }

#pragma unroll
  for (int j = 0; j < 4; ++j) {
    int col = colBase + wn * 64 + j * 16 + l15;
    float bb = b1p[col];
#pragma unroll
    for (int i = 0; i < 4; ++i) {
#pragma unroll
      for (int r = 0; r < 4; ++r) {
        int lrow = wm * 64 + i * 16 + quad * 4 + r;
        float v = acc[i][j][r] + bb;
        v = 0.5f * v * (1.0f + erff(v * 0.70710678118654752f));
        h[(size_t)(rowBase + lrow) * HID + col] = f2bf(v);
      }
    }
  }
}

__global__ __launch_bounds__(256, 2) void gemm2_kernel(
    const unsigned short* __restrict__ h, const float* __restrict__ W2,
    const float* __restrict__ b2, const int* __restrict__ meta,
    const int* __restrict__ gtok, const float* __restrict__ gw,
    float* __restrict__ out) {
  int tileId = blockIdx.y;
  if (tileId >= meta[MI_NTILES]) return;
  int e = meta[MI_TILEEXP + tileId];
  int rowBase = meta[MI_TILEROW + tileId];
  int colBase = blockIdx.x * 128;
  const float* Bp = W2 + (size_t)e * HID * DIM + colBase;
  const float* b2p = b2 + (size_t)e * DIM;

  __shared__ __align__(16) unsigned short As[128 * 32];
  __shared__ __align__(16) unsigned short Bs[128 * 32];

  int tid = threadIdx.x;
  int arow = tid >> 1, aseg = (tid & 1) * 16;
  const unsigned short* ap = h + (size_t)(rowBase + arow) * HID + aseg;
  int bk = (tid & 15) * 2;
  int bn = (tid >> 4) * 8;
  const float* bp = Bp + (size_t)bk * DIM + bn;

  int lane = tid & 63, wv = tid >> 6;
  int wm = wv & 1, wn = wv >> 1;
  int l15 = lane & 15, quad = lane >> 4;

  floatx4 acc[4][4];
#pragma unroll
  for (int i = 0; i < 4; ++i)
#pragma unroll
    for (int j = 0; j < 4; ++j) acc[i][j] = (floatx4){0.f, 0.f, 0.f, 0.f};

  for (int kc = 0; kc < HID / 32; ++kc) {
    uint4 h0 = *(const uint4*)(ap + kc * 32);
    uint4 h1 = *(const uint4*)(ap + kc * 32 + 8);
    const float* bpk = bp + (size_t)kc * 32 * DIM;
    float4 r00 = ((const float4*)bpk)[0], r01 = ((const float4*)bpk)[1];
    float4 r10 = ((const float4*)(bpk + DIM))[0], r11 = ((const float4*)(bpk + DIM))[1];

    *(uint4*)&As[arow * 32 + aseg] = h0;
    *(uint4*)&As[arow * 32 + aseg + 8] = h1;
    unsigned int pr[8] = {pack2(r00.x, r10.x), pack2(r00.y, r10.y),
                          pack2(r00.z, r10.z), pack2(r00.w, r10.w),
                          pack2(r01.x, r11.x), pack2(r01.y, r11.y),
                          pack2(r01.z, r11.z), pack2(r01.w, r11.w)};
#pragma unroll
    for (int j = 0; j < 8; ++j)
      *(unsigned int*)&Bs[(bn + j) * 32 + bk] = pr[j];
    __syncthreads();

    short8 af[4], bfr[4];
#pragma unroll
    for (int i = 0; i < 4; ++i)
      af[i] = *(const short8*)&As[(wm * 64 + i * 16 + l15) * 32 + quad * 8];
#pragma unroll
    for (int j = 0; j < 4; ++j)
      bfr[j] = *(const short8*)&Bs[(wn * 64 + j * 16 + l15) * 32 + quad * 8];
#pragma unroll
    for (int i = 0; i < 4; ++i)
#pragma unroll
      for (int j = 0; j < 4; ++j)
        acc[i][j] = __builtin_amdgcn_mfma_f32_16x16x32_bf16(af[i], bfr[j], acc[i][j], 0, 0, 0);
    __syncthreads();
  }

  int toks[16]; float wts[16];
#pragma unroll
  for (int i = 0; i < 4; ++i)
#pragma unroll
    for (int r = 0; r < 4; ++r) {
      int grow = rowBase + wm * 64 + i * 16 + quad * 4 + r;
      toks[i * 4 + r] = gtok[grow];
      wts[i * 4 + r] = gw[grow];
    }
#pragma unroll
  for (int j = 0; j < 4; ++j) {
    int col = colBase + wn * 64 + j * 16 + l15;
    float bb = b2p[col];
#pragma unroll
    for (int i = 0; i < 4; ++i) {
#pragma unroll
      for (int r = 0; r < 4; ++r) {
        int tokr = toks[i * 4 + r];
        if (tokr >= 0)
          atomicAdd(out + (size_t)tokr * DIM + col, wts[i * 4 + r] * (acc[i][j][r] + bb));
      }
    }
  }
}

__global__ void ws_diag_kernel(float* o, float v) { o[0] = v; }

extern "C" void kernel_launch(void* const* d_in, const int* in_sizes, int n_in,
                              void* d_out, int out_size, void* d_ws, size_t ws_size,
                              hipStream_t stream) {
  const float* x  = (const float*)d_in[0];
  const float* Wr = (const float*)d_in[1];
  const float* W1 = (const float*)d_in[2];
  const float* b1 = (const float*)d_in[3];
  const float* W2 = (const float*)d_in[4];
  const float* b2 = (const float*)d_in[5];
  float* out = (float*)d_out;
  char* ws = (char*)d_ws;

  if (ws_size < WS_NEED) {
    hipMemsetAsync(d_out, 0, (size_t)out_size * sizeof(float), stream);
    ws_diag_kernel<<<1, 1, 0, stream>>>(out, (float)ws_size);
    return;
  }

  int* meta = (int*)ws;
  int* tokE = (int*)(ws + WS_TOKE);
  float* tokW = (float*)(ws + WS_TOKW);
  int* gtok = (int*)(ws + WS_GTOK);
  float* gw = (float*)(ws + WS_GW);
  unsigned short* h = (unsigned short*)(ws + WS_H);

  hipMemsetAsync(meta, 0, 4096, stream);
  hipMemsetAsync(d_out, 0, (size_t)N_TOKENS * DIM * sizeof(float), stream);
  hipMemsetAsync(gtok, 0xFF, (size_t)RCAP * 4, stream);
  hipMemsetAsync(gw, 0, (size_t)RCAP * 4, stream);

  if (ws_size >= WS_NEED2) {
    unsigned short* xb = (unsigned short*)(ws + WS_XB);
    unsigned short* wt = (unsigned short*)(ws + WS_WT);
    router_kernel<<<N_TOKENS / 4, 256, 0, stream>>>(x, Wr, meta, tokE, tokW, xb);
    offsets_kernel<<<1, 64, 0, stream>>>(meta, out);
    scatter_kernel<<<N_TOKENS / 256, 256, 0, stream>>>(meta, tokE, tokW, gtok, gw);
    convw_kernel<<<dim3(HID / 64, DIM / 64, NEXP), 256, 0, stream>>>(W1, wt, DIM, HID);
    gemm1b_kernel<<<dim3(MAXTILES, HID / 128), 256, 0, stream>>>(xb, wt, b1, meta, gtok, h);
    convw_kernel<<<dim3(DIM / 64, HID / 64, NEXP), 256, 0, stream>>>(W2, wt, HID, DIM);
    gemm2b_kernel<<<dim3(MAXTILES, DIM / 128), 256, 0, stream>>>(h, wt, b2, meta, gtok, gw, out);
  } else {
    router_kernel<<<N_TOKENS / 4, 256, 0, stream>>>(x, Wr, meta, tokE, tokW, nullptr);
    offsets_kernel<<<1, 64, 0, stream>>>(meta, out);
    scatter_kernel<<<N_TOKENS / 256, 256, 0, stream>>>(meta, tokE, tokW, gtok, gw);
    gemm1_kernel<<<dim3(HID / 128, MAXTILES), 256, 0, stream>>>(x, W1, b1, meta, gtok, h);
    gemm2_kernel<<<dim3(DIM / 128, MAXTILES), 256, 0, stream>>>(h, W2, b2, meta, gtok, gw, out);
  }
}

// Round 2
// 2555.515 us; speedup vs baseline: 1.6416x; 1.6416x over previous
//
#include <hip/hip_runtime.h>
#include <math.h>

#define N_TOKENS 16384
#define DIM 2048
#define HID 4096
#define NEXP 8
#define TOPK 2
#define RCAP 33792      // 264 tiles * 128 rows (max padded rows)
#define MAXTILES 264

// meta layout (int indices into ws[0..4096))
#define MI_CNT 0        // int[8]  expert counts
#define MI_FILL 8       // int[8]  scatter fill counters
#define MI_USAGE 16     // float[8] usage sums (softmax prob sums)
#define MI_NTILES 24    // int     number of 128-row tiles
#define MI_EXPOFF 32    // int[9]  padded expert row offsets
#define MI_TILEEXP 64   // int[264] tile -> expert
#define MI_TILEROW 384  // int[264] tile -> padded row base

// ws byte offsets
#define WS_TOKE 4096
#define WS_TOKW (WS_TOKE + 131072)
#define WS_GTOK (WS_TOKW + 131072)
#define WS_GW   (WS_GTOK + 135168)
#define WS_H    1048576
#define WS_NEED (WS_H + (size_t)RCAP * HID * 2)            // old path: ~278 MB
#define WS_XB   WS_NEED                                     // bf16 x: 67 MB
#define WS_WT   (WS_XB + (size_t)N_TOKENS * DIM * 2)        // bf16 W^T (shared W1/W2): 134 MB
#define WS_NEED2 (WS_WT + (size_t)NEXP * DIM * HID * 2)     // ~457 MiB total

typedef __attribute__((ext_vector_type(8))) short short8;
typedef __attribute__((ext_vector_type(8))) unsigned short ushort8;
typedef __attribute__((ext_vector_type(4))) float floatx4;
typedef __attribute__((ext_vector_type(2))) unsigned int uintx2;

static __device__ __forceinline__ unsigned short f2bf(float f) {
  unsigned int u = __float_as_uint(f);
  u += 0x7fffu + ((u >> 16) & 1u);   // round-to-nearest-even
  return (unsigned short)(u >> 16);
}
static __device__ __forceinline__ unsigned int pack2(float a, float b) {
  return (unsigned int)f2bf(a) | ((unsigned int)f2bf(b) << 16);
}

// async global->LDS, 16B per lane, LDS dest = wave-uniform base + lane*16
static __device__ __forceinline__ void gload16(const void* g, void* l) {
  __builtin_amdgcn_global_load_lds(
      (__attribute__((address_space(1))) void*)(void*)g,
      (__attribute__((address_space(3))) void*)l, 16, 0, 0);
}

// ---------------- router: 1 wave per token, fp64 logits; NO global atomics ----------------
// Emits: tokE/tokW (top-2), tokP (all 8 probs, for usage reduction), optional bf16 x.
__global__ __launch_bounds__(256) void router_kernel(
    const float* __restrict__ x, const float* __restrict__ Wr,
    int* __restrict__ tokE, float* __restrict__ tokW, float* __restrict__ tokP,
    unsigned short* __restrict__ xb) {
  int wv = threadIdx.x >> 6, lane = threadIdx.x & 63;
  int t = blockIdx.x * 4 + wv;
  const float4* xr = (const float4*)(x + (size_t)t * DIM);
  double acc[8];
#pragma unroll
  for (int e = 0; e < 8; ++e) acc[e] = 0.0;
#pragma unroll
  for (int i = 0; i < 8; ++i) {
    int d4 = i * 64 + lane;               // float4 index in [0,512)
    float4 xv = xr[d4];
    if (xb) {
      uintx2 p = {pack2(xv.x, xv.y), pack2(xv.z, xv.w)};
      *(uintx2*)(xb + (size_t)t * DIM + d4 * 4) = p;
    }
    const float* wr = Wr + (size_t)d4 * 32;  // 4 rows of 8 floats
    float xs[4] = {xv.x, xv.y, xv.z, xv.w};
#pragma unroll
    for (int j = 0; j < 4; ++j) {
      float4 w0 = *(const float4*)(wr + j * 8);
      float4 w1 = *(const float4*)(wr + j * 8 + 4);
      double xd = (double)xs[j];
      acc[0] += xd * (double)w0.x; acc[1] += xd * (double)w0.y;
      acc[2] += xd * (double)w0.z; acc[3] += xd * (double)w0.w;
      acc[4] += xd * (double)w1.x; acc[5] += xd * (double)w1.y;
      acc[6] += xd * (double)w1.z; acc[7] += xd * (double)w1.w;
    }
  }
#pragma unroll
  for (int off = 32; off > 0; off >>= 1) {
#pragma unroll
    for (int e = 0; e < 8; ++e) acc[e] += __shfl_down(acc[e], off);
  }
  if (lane == 0) {
    double m = acc[0];
#pragma unroll
    for (int e = 1; e < 8; ++e) m = acc[e] > m ? acc[e] : m;
    double p[8], s = 0.0;
#pragma unroll
    for (int e = 0; e < 8; ++e) { p[e] = exp(acc[e] - m); s += p[e]; }
    double inv = 1.0 / s;
    float4 pr0 = {(float)(p[0] * inv), (float)(p[1] * inv),
                  (float)(p[2] * inv), (float)(p[3] * inv)};
    float4 pr1 = {(float)(p[4] * inv), (float)(p[5] * inv),
                  (float)(p[6] * inv), (float)(p[7] * inv)};
    *(float4*)(tokP + (size_t)t * 8) = pr0;
    *(float4*)(tokP + (size_t)t * 8 + 4) = pr1;
    int i0 = 0; double b0 = p[0];
#pragma unroll
    for (int e = 1; e < 8; ++e) if (p[e] > b0) { b0 = p[e]; i0 = e; }
    int i1 = -1; double b1v = -1.0;
#pragma unroll
    for (int e = 0; e < 8; ++e) if (e != i0 && p[e] > b1v) { b1v = p[e]; i1 = e; }
    double den = p[i0] + p[i1];
    tokE[2 * t] = i0; tokE[2 * t + 1] = i1;
    tokW[2 * t] = (float)(p[i0] / den); tokW[2 * t + 1] = (float)(p[i1] / den);
  }
}

// ---------------- hist: usage sums + expert counts, LDS-aggregated ----------------
__global__ __launch_bounds__(256) void hist_kernel(
    const float* __restrict__ tokP, const int* __restrict__ tokE,
    int* __restrict__ meta) {
  int tid = threadIdx.x;
  int t = blockIdx.x * 256 + tid;
  __shared__ float lus[8];
  __shared__ int lcnt[8];
  if (tid < 8) { lus[tid] = 0.f; lcnt[tid] = 0; }
  __syncthreads();
  float4 pa = *(const float4*)(tokP + (size_t)t * 8);
  float4 pb = *(const float4*)(tokP + (size_t)t * 8 + 4);
  float p[8] = {pa.x, pa.y, pa.z, pa.w, pb.x, pb.y, pb.z, pb.w};
#pragma unroll
  for (int off = 32; off > 0; off >>= 1) {
#pragma unroll
    for (int e = 0; e < 8; ++e) p[e] += __shfl_down(p[e], off);
  }
  if ((tid & 63) == 0) {
#pragma unroll
    for (int e = 0; e < 8; ++e) atomicAdd(&lus[e], p[e]);
  }
  atomicAdd(&lcnt[tokE[2 * t]], 1);
  atomicAdd(&lcnt[tokE[2 * t + 1]], 1);
  __syncthreads();
  if (tid < 8) {
    atomicAdd((float*)(meta + MI_USAGE) + tid, lus[tid]);
    atomicAdd(&meta[MI_CNT + tid], lcnt[tid]);
  }
}

// ---------------- offsets + tile map + loss ----------------
__global__ __launch_bounds__(64) void offsets_kernel(
    int* __restrict__ meta, float* __restrict__ out) {
  if (threadIdx.x == 0) {
    int off = 0, nt = 0;
    for (int e = 0; e < NEXP; ++e) {
      meta[MI_EXPOFF + e] = off;
      int c = meta[MI_CNT + e];
      int ntile = (c + 127) >> 7;
      for (int i = 0; i < ntile; ++i) {
        meta[MI_TILEEXP + nt] = e;
        meta[MI_TILEROW + nt] = off + i * 128;
        ++nt;
      }
      off += ntile * 128;
    }
    meta[MI_NTILES] = nt;
    float* usage = (float*)(meta + MI_USAGE);
    double loss = 0.0;
    for (int e = 0; e < NEXP; ++e)
      loss += ((double)usage[e] / N_TOKENS) *
              ((double)meta[MI_CNT + e] / (double)(N_TOKENS * TOPK));
    out[(size_t)N_TOKENS * DIM] = (float)(NEXP * loss);
  }
}

// ---------------- scatter tokens into expert-grouped rows (LDS-aggregated) ----------------
__global__ __launch_bounds__(256) void scatter_kernel(
    int* __restrict__ meta, const int* __restrict__ tokE,
    const float* __restrict__ tokW, int* __restrict__ gtok,
    float* __restrict__ gw) {
  int tid = threadIdx.x;
  int t = blockIdx.x * 256 + tid;
  __shared__ int lcnt[8];
  __shared__ int lbase[8];
  if (tid < 8) lcnt[tid] = 0;
  __syncthreads();
  int e0 = tokE[2 * t], e1 = tokE[2 * t + 1];
  float w0 = tokW[2 * t], w1 = tokW[2 * t + 1];
  int r0 = atomicAdd(&lcnt[e0], 1);
  int r1 = atomicAdd(&lcnt[e1], 1);
  __syncthreads();
  if (tid < 8) lbase[tid] = atomicAdd(&meta[MI_FILL + tid], lcnt[tid]);
  __syncthreads();
  int idx0 = meta[MI_EXPOFF + e0] + lbase[e0] + r0;
  gtok[idx0] = t; gw[idx0] = w0;
  int idx1 = meta[MI_EXPOFF + e1] + lbase[e1] + r1;
  gtok[idx1] = t; gw[idx1] = w1;
}

// ---------------- weight convert+transpose: W[e][K][N] fp32 -> WT[e][N][K] bf16 ----------------
__global__ __launch_bounds__(256) void convw_kernel(
    const float* __restrict__ W, unsigned short* __restrict__ WT, int K, int N) {
  int e = blockIdx.z;
  int nBase = blockIdx.x * 64, kBase = blockIdx.y * 64;
  __shared__ __align__(16) unsigned short ldsT[64][72];  // [n][k], pad 8
  int tid = threadIdx.x;
  const float* Wp = W + (size_t)e * K * N;
#pragma unroll
  for (int it = 0; it < 4; ++it) {
    int k = it * 16 + (tid >> 4);
    int n4 = (tid & 15) * 4;
    float4 v = *(const float4*)(Wp + (size_t)(kBase + k) * N + nBase + n4);
    ldsT[n4 + 0][k] = f2bf(v.x);
    ldsT[n4 + 1][k] = f2bf(v.y);
    ldsT[n4 + 2][k] = f2bf(v.z);
    ldsT[n4 + 3][k] = f2bf(v.w);
  }
  __syncthreads();
  unsigned short* WTp = WT + (size_t)e * N * K;
#pragma unroll
  for (int it = 0; it < 2; ++it) {
    int n = it * 32 + (tid >> 3);
    int sg = tid & 7;
    ushort8 u = *(const ushort8*)&ldsT[n][sg * 8];
    *(ushort8*)(WTp + (size_t)(nBase + n) * K + kBase + sg * 8) = u;
  }
}

// ================= bf16 GEMMs: 128x128 tile, BK=64, global_load_lds + XOR swizzle =================
__global__ __launch_bounds__(256, 2) void gemm1b_kernel(
    const unsigned short* __restrict__ xb, const unsigned short* __restrict__ w1t,
    const float* __restrict__ b1, const int* __restrict__ meta,
    const int* __restrict__ gtok, unsigned short* __restrict__ h) {
  int tileId = blockIdx.x;                 // tile-major dispatch: B panel stays L2-hot
  if (tileId >= meta[MI_NTILES]) return;
  int e = meta[MI_TILEEXP + tileId];
  int rowBase = meta[MI_TILEROW + tileId];
  int colBase = blockIdx.y * 128;
  const float* b1p = b1 + (size_t)e * HID;

  __shared__ __align__(16) unsigned short As[128 * 64];
  __shared__ __align__(16) unsigned short Bs[128 * 64];

  int tid = threadIdx.x;
  int s = tid & 7, rsub = tid >> 3;        // row-sub in [0,32), 8 lanes x 16B per row
  int sx = ((s ^ (rsub & 7)) * 8);         // swizzled element offset within 64-elem row

  const unsigned short* aSrc[4];
  const unsigned short* bSrc[4];
#pragma unroll
  for (int c = 0; c < 4; ++c) {
    int r = c * 32 + rsub;
    int tok = gtok[rowBase + r]; if (tok < 0) tok = 0;
    aSrc[c] = xb + (size_t)tok * DIM + sx;
    bSrc[c] = w1t + ((size_t)e * HID + colBase + r) * DIM + sx;
  }
  int lane = tid & 63, wv = tid >> 6;
  int wm = wv & 1, wn = wv >> 1;
  int l15 = lane & 15, quad = lane >> 4;
  unsigned short* aLds[4];
  unsigned short* bLds[4];
#pragma unroll
  for (int c = 0; c < 4; ++c) {
    aLds[c] = As + (c * 32 + wv * 8) * 64;
    bLds[c] = Bs + (c * 32 + wv * 8) * 64;
  }

  floatx4 acc[4][4];
#pragma unroll
  for (int i = 0; i < 4; ++i)
#pragma unroll
    for (int j = 0; j < 4; ++j) acc[i][j] = (floatx4){0.f, 0.f, 0.f, 0.f};

  for (int kc = 0; kc < DIM / 64; ++kc) {
#pragma unroll
    for (int c = 0; c < 4; ++c) gload16(aSrc[c] + kc * 64, aLds[c]);
#pragma unroll
    for (int c = 0; c < 4; ++c) gload16(bSrc[c] + kc * 64, bLds[c]);
    __syncthreads();
#pragma unroll
    for (int ks = 0; ks < 2; ++ks) {
      short8 af[4], bfr[4];
#pragma unroll
      for (int i = 0; i < 4; ++i) {
        int R = wm * 64 + i * 16 + l15;
        int off = R * 128 + (((ks << 6) | (quad << 4)) ^ ((R & 7) << 4));
        af[i] = *(const short8*)((const char*)As + off);
      }
#pragma unroll
      for (int j = 0; j < 4; ++j) {
        int R = wn * 64 + j * 16 + l15;
        int off = R * 128 + (((ks << 6) | (quad << 4)) ^ ((R & 7) << 4));
        bfr[j] = *(const short8*)((const char*)Bs + off);
      }
#pragma unroll
      for (int i = 0; i < 4; ++i)
#pragma unroll
        for (int j = 0; j < 4; ++j)
          acc[i][j] = __builtin_amdgcn_mfma_f32_16x16x32_bf16(af[i], bfr[j], acc[i][j], 0, 0, 0);
    }
    __syncthreads();
  }

#pragma unroll
  for (int j = 0; j < 4; ++j) {
    int col = colBase + wn * 64 + j * 16 + l15;
    float bb = b1p[col];
#pragma unroll
    for (int i = 0; i < 4; ++i) {
#pragma unroll
      for (int r = 0; r < 4; ++r) {
        int lrow = wm * 64 + i * 16 + quad * 4 + r;
        float v = acc[i][j][r] + bb;
        v = 0.5f * v * (1.0f + erff(v * 0.70710678118654752f));
        h[(size_t)(rowBase + lrow) * HID + col] = f2bf(v);
      }
    }
  }
}

__global__ __launch_bounds__(256, 2) void gemm2b_kernel(
    const unsigned short* __restrict__ h, const unsigned short* __restrict__ w2t,
    const float* __restrict__ b2, const int* __restrict__ meta,
    const int* __restrict__ gtok, const float* __restrict__ gw,
    float* __restrict__ out) {
  int tileId = blockIdx.x;
  if (tileId >= meta[MI_NTILES]) return;
  int e = meta[MI_TILEEXP + tileId];
  int rowBase = meta[MI_TILEROW + tileId];
  int colBase = blockIdx.y * 128;
  const float* b2p = b2 + (size_t)e * DIM;

  __shared__ __align__(16) unsigned short As[128 * 64];
  __shared__ __align__(16) unsigned short Bs[128 * 64];

  int tid = threadIdx.x;
  int s = tid & 7, rsub = tid >> 3;
  int sx = ((s ^ (rsub & 7)) * 8);

  const unsigned short* aSrc[4];
  const unsigned short* bSrc[4];
#pragma unroll
  for (int c = 0; c < 4; ++c) {
    int r = c * 32 + rsub;
    aSrc[c] = h + (size_t)(rowBase + r) * HID + sx;
    bSrc[c] = w2t + ((size_t)e * DIM + colBase + r) * HID + sx;
  }
  int lane = tid & 63, wv = tid >> 6;
  int wm = wv & 1, wn = wv >> 1;
  int l15 = lane & 15, quad = lane >> 4;
  unsigned short* aLds[4];
  unsigned short* bLds[4];
#pragma unroll
  for (int c = 0; c < 4; ++c) {
    aLds[c] = As + (c * 32 + wv * 8) * 64;
    bLds[c] = Bs + (c * 32 + wv * 8) * 64;
  }

  floatx4 acc[4][4];
#pragma unroll
  for (int i = 0; i < 4; ++i)
#pragma unroll
    for (int j = 0; j < 4; ++j) acc[i][j] = (floatx4){0.f, 0.f, 0.f, 0.f};

  for (int kc = 0; kc < HID / 64; ++kc) {
#pragma unroll
    for (int c = 0; c < 4; ++c) gload16(aSrc[c] + kc * 64, aLds[c]);
#pragma unroll
    for (int c = 0; c < 4; ++c) gload16(bSrc[c] + kc * 64, bLds[c]);
    __syncthreads();
#pragma unroll
    for (int ks = 0; ks < 2; ++ks) {
      short8 af[4], bfr[4];
#pragma unroll
      for (int i = 0; i < 4; ++i) {
        int R = wm * 64 + i * 16 + l15;
        int off = R * 128 + (((ks << 6) | (quad << 4)) ^ ((R & 7) << 4));
        af[i] = *(const short8*)((const char*)As + off);
      }
#pragma unroll
      for (int j = 0; j < 4; ++j) {
        int R = wn * 64 + j * 16 + l15;
        int off = R * 128 + (((ks << 6) | (quad << 4)) ^ ((R & 7) << 4));
        bfr[j] = *(const short8*)((const char*)Bs + off);
      }
#pragma unroll
      for (int i = 0; i < 4; ++i)
#pragma unroll
        for (int j = 0; j < 4; ++j)
          acc[i][j] = __builtin_amdgcn_mfma_f32_16x16x32_bf16(af[i], bfr[j], acc[i][j], 0, 0, 0);
    }
    __syncthreads();
  }

  int toks[16]; float wts[16];
#pragma unroll
  for (int i = 0; i < 4; ++i)
#pragma unroll
    for (int r = 0; r < 4; ++r) {
      int grow = rowBase + wm * 64 + i * 16 + quad * 4 + r;
      toks[i * 4 + r] = gtok[grow];
      wts[i * 4 + r] = gw[grow];
    }
#pragma unroll
  for (int j = 0; j < 4; ++j) {
    int col = colBase + wn * 64 + j * 16 + l15;
    float bb = b2p[col];
#pragma unroll
    for (int i = 0; i < 4; ++i) {
#pragma unroll
      for (int r = 0; r < 4; ++r) {
        int tokr = toks[i * 4 + r];
        if (tokr >= 0)
          atomicAdd(out + (size_t)tokr * DIM + col, wts[i * 4 + r] * (acc[i][j][r] + bb));
      }
    }
  }
}

// ================= OLD fp32-operand GEMMs (fallback when ws is small) =================
__global__ __launch_bounds__(256, 2) void gemm1_kernel(
    const float* __restrict__ x, const float* __restrict__ W1,
    const float* __restrict__ b1, const int* __restrict__ meta,
    const int* __restrict__ gtok, unsigned short* __restrict__ h) {
  int tileId = blockIdx.y;
  if (tileId >= meta[MI_NTILES]) return;
  int e = meta[MI_TILEEXP + tileId];
  int rowBase = meta[MI_TILEROW + tileId];
  int colBase = blockIdx.x * 128;
  const float* Bp = W1 + (size_t)e * DIM * HID + colBase;
  const float* b1p = b1 + (size_t)e * HID;

  __shared__ __align__(16) unsigned short As[128 * 32];
  __shared__ __align__(16) unsigned short Bs[128 * 32];

  int tid = threadIdx.x;
  int arow = tid >> 1, aseg = (tid & 1) * 16;
  int tok = gtok[rowBase + arow];
  const float* ap = x + (size_t)(tok >= 0 ? tok : 0) * DIM + aseg;
  int bk = (tid & 15) * 2;
  int bn = (tid >> 4) * 8;
  const float* bp = Bp + (size_t)bk * HID + bn;

  int lane = tid & 63, wv = tid >> 6;
  int wm = wv & 1, wn = wv >> 1;
  int l15 = lane & 15, quad = lane >> 4;

  floatx4 acc[4][4];
#pragma unroll
  for (int i = 0; i < 4; ++i)
#pragma unroll
    for (int j = 0; j < 4; ++j) acc[i][j] = (floatx4){0.f, 0.f, 0.f, 0.f};

  for (int kc = 0; kc < DIM / 32; ++kc) {
    float4 a0, a1, a2, a3;
    if (tok >= 0) {
      const float4* av = (const float4*)(ap + kc * 32);
      a0 = av[0]; a1 = av[1]; a2 = av[2]; a3 = av[3];
    } else {
      a0 = a1 = a2 = a3 = (float4){0.f, 0.f, 0.f, 0.f};
    }
    const float* bpk = bp + (size_t)kc * 32 * HID;
    float4 r00 = ((const float4*)bpk)[0], r01 = ((const float4*)bpk)[1];
    float4 r10 = ((const float4*)(bpk + HID))[0], r11 = ((const float4*)(bpk + HID))[1];

    uint4 pa0 = {pack2(a0.x, a0.y), pack2(a0.z, a0.w), pack2(a1.x, a1.y), pack2(a1.z, a1.w)};
    uint4 pa1 = {pack2(a2.x, a2.y), pack2(a2.z, a2.w), pack2(a3.x, a3.y), pack2(a3.z, a3.w)};
    *(uint4*)&As[arow * 32 + aseg] = pa0;
    *(uint4*)&As[arow * 32 + aseg + 8] = pa1;

    unsigned int pr[8] = {pack2(r00.x, r10.x), pack2(r00.y, r10.y),
                          pack2(r00.z, r10.z), pack2(r00.w, r10.w),
                          pack2(r01.x, r11.x), pack2(r01.y, r11.y),
                          pack2(r01.z, r11.z), pack2(r01.w, r11.w)};
#pragma unroll
    for (int j = 0; j < 8; ++j)
      *(unsigned int*)&Bs[(bn + j) * 32 + bk] = pr[j];
    __syncthreads();

    short8 af[4], bfr[4];
#pragma unroll
    for (int i = 0; i < 4; ++i)
      af[i] = *(const short8*)&As[(wm * 64 + i * 16 + l15) * 32 + quad * 8];
#pragma unroll
    for (int j = 0; j < 4; ++j)
      bfr[j] = *(const short8*)&Bs[(wn * 64 + j * 16 + l15) * 32 + quad * 8];
#pragma unroll
    for (int i = 0; i < 4; ++i)
#pragma unroll
      for (int j = 0; j < 4; ++j)
        acc[i][j] = __builtin_amdgcn_mfma_f32_16x16x32_bf16(af[i], bfr[j], acc[i][j], 0, 0, 0);
    __syncthreads();
  }

#pragma unroll
  for (int j = 0; j < 4; ++j) {
    int col = colBase + wn * 64 + j * 16 + l15;
    float bb = b1p[col];
#pragma unroll
    for (int i = 0; i < 4; ++i) {
#pragma unroll
      for (int r = 0; r < 4; ++r) {
        int lrow = wm * 64 + i * 16 + quad * 4 + r;
        float v = acc[i][j][r] + bb;
        v = 0.5f * v * (1.0f + erff(v * 0.70710678118654752f));
        h[(size_t)(rowBase + lrow) * HID + col] = f2bf(v);
      }
    }
  }
}

__global__ __launch_bounds__(256, 2) void gemm2_kernel(
    const unsigned short* __restrict__ h, const float* __restrict__ W2,
    const float* __restrict__ b2, const int* __restrict__ meta,
    const int* __restrict__ gtok, const float* __restrict__ gw,
    float* __restrict__ out) {
  int tileId = blockIdx.y;
  if (tileId >= meta[MI_NTILES]) return;
  int e = meta[MI_TILEEXP + tileId];
  int rowBase = meta[MI_TILEROW + tileId];
  int colBase = blockIdx.x * 128;
  const float* Bp = W2 + (size_t)e * HID * DIM + colBase;
  const float* b2p = b2 + (size_t)e * DIM;

  __shared__ __align__(16) unsigned short As[128 * 32];
  __shared__ __align__(16) unsigned short Bs[128 * 32];

  int tid = threadIdx.x;
  int arow = tid >> 1, aseg = (tid & 1) * 16;
  const unsigned short* ap = h + (size_t)(rowBase + arow) * HID + aseg;
  int bk = (tid & 15) * 2;
  int bn = (tid >> 4) * 8;
  const float* bp = Bp + (size_t)bk * DIM + bn;

  int lane = tid & 63, wv = tid >> 6;
  int wm = wv & 1, wn = wv >> 1;
  int l15 = lane & 15, quad = lane >> 4;

  floatx4 acc[4][4];
#pragma unroll
  for (int i = 0; i < 4; ++i)
#pragma unroll
    for (int j = 0; j < 4; ++j) acc[i][j] = (floatx4){0.f, 0.f, 0.f, 0.f};

  for (int kc = 0; kc < HID / 32; ++kc) {
    uint4 h0 = *(const uint4*)(ap + kc * 32);
    uint4 h1 = *(const uint4*)(ap + kc * 32 + 8);
    const float* bpk = bp + (size_t)kc * 32 * DIM;
    float4 r00 = ((const float4*)bpk)[0], r01 = ((const float4*)bpk)[1];
    float4 r10 = ((const float4*)(bpk + DIM))[0], r11 = ((const float4*)(bpk + DIM))[1];

    *(uint4*)&As[arow * 32 + aseg] = h0;
    *(uint4*)&As[arow * 32 + aseg + 8] = h1;
    unsigned int pr[8] = {pack2(r00.x, r10.x), pack2(r00.y, r10.y),
                          pack2(r00.z, r10.z), pack2(r00.w, r10.w),
                          pack2(r01.x, r11.x), pack2(r01.y, r11.y),
                          pack2(r01.z, r11.z), pack2(r01.w, r11.w)};
#pragma unroll
    for (int j = 0; j < 8; ++j)
      *(unsigned int*)&Bs[(bn + j) * 32 + bk] = pr[j];
    __syncthreads();

    short8 af[4], bfr[4];
#pragma unroll
    for (int i = 0; i < 4; ++i)
      af[i] = *(const short8*)&As[(wm * 64 + i * 16 + l15) * 32 + quad * 8];
#pragma unroll
    for (int j = 0; j < 4; ++j)
      bfr[j] = *(const short8*)&Bs[(wn * 64 + j * 16 + l15) * 32 + quad * 8];
#pragma unroll
    for (int i = 0; i < 4; ++i)
#pragma unroll
      for (int j = 0; j < 4; ++j)
        acc[i][j] = __builtin_amdgcn_mfma_f32_16x16x32_bf16(af[i], bfr[j], acc[i][j], 0, 0, 0);
    __syncthreads();
  }

  int toks[16]; float wts[16];
#pragma unroll
  for (int i = 0; i < 4; ++i)
#pragma unroll
    for (int r = 0; r < 4; ++r) {
      int grow = rowBase + wm * 64 + i * 16 + quad * 4 + r;
      toks[i * 4 + r] = gtok[grow];
      wts[i * 4 + r] = gw[grow];
    }
#pragma unroll
  for (int j = 0; j < 4; ++j) {
    int col = colBase + wn * 64 + j * 16 + l15;
    float bb = b2p[col];
#pragma unroll
    for (int i = 0; i < 4; ++i) {
#pragma unroll
      for (int r = 0; r < 4; ++r) {
        int tokr = toks[i * 4 + r];
        if (tokr >= 0)
          atomicAdd(out + (size_t)tokr * DIM + col, wts[i * 4 + r] * (acc[i][j][r] + bb));
      }
    }
  }
}

__global__ void ws_diag_kernel(float* o, float v) { o[0] = v; }

extern "C" void kernel_launch(void* const* d_in, const int* in_sizes, int n_in,
                              void* d_out, int out_size, void* d_ws, size_t ws_size,
                              hipStream_t stream) {
  const float* x  = (const float*)d_in[0];
  const float* Wr = (const float*)d_in[1];
  const float* W1 = (const float*)d_in[2];
  const float* b1 = (const float*)d_in[3];
  const float* W2 = (const float*)d_in[4];
  const float* b2 = (const float*)d_in[5];
  float* out = (float*)d_out;
  char* ws = (char*)d_ws;

  if (ws_size < WS_NEED) {
    hipMemsetAsync(d_out, 0, (size_t)out_size * sizeof(float), stream);
    ws_diag_kernel<<<1, 1, 0, stream>>>(out, (float)ws_size);
    return;
  }

  int* meta = (int*)ws;
  int* tokE = (int*)(ws + WS_TOKE);
  float* tokW = (float*)(ws + WS_TOKW);
  int* gtok = (int*)(ws + WS_GTOK);
  float* gw = (float*)(ws + WS_GW);
  unsigned short* h = (unsigned short*)(ws + WS_H);
  // tokP lives in the h region: consumed by hist before gemm1 writes h.
  float* tokP = (float*)(ws + WS_H);

  hipMemsetAsync(meta, 0, 4096, stream);
  hipMemsetAsync(d_out, 0, (size_t)N_TOKENS * DIM * sizeof(float), stream);
  hipMemsetAsync(gtok, 0xFF, (size_t)RCAP * 4, stream);
  hipMemsetAsync(gw, 0, (size_t)RCAP * 4, stream);

  if (ws_size >= WS_NEED2) {
    unsigned short* xb = (unsigned short*)(ws + WS_XB);
    unsigned short* wt = (unsigned short*)(ws + WS_WT);
    router_kernel<<<N_TOKENS / 4, 256, 0, stream>>>(x, Wr, tokE, tokW, tokP, xb);
    hist_kernel<<<N_TOKENS / 256, 256, 0, stream>>>(tokP, tokE, meta);
    offsets_kernel<<<1, 64, 0, stream>>>(meta, out);
    scatter_kernel<<<N_TOKENS / 256, 256, 0, stream>>>(meta, tokE, tokW, gtok, gw);
    convw_kernel<<<dim3(HID / 64, DIM / 64, NEXP), 256, 0, stream>>>(W1, wt, DIM, HID);
    gemm1b_kernel<<<dim3(MAXTILES, HID / 128), 256, 0, stream>>>(xb, wt, b1, meta, gtok, h);
    convw_kernel<<<dim3(DIM / 64, HID / 64, NEXP), 256, 0, stream>>>(W2, wt, HID, DIM);
    gemm2b_kernel<<<dim3(MAXTILES, DIM / 128), 256, 0, stream>>>(h, wt, b2, meta, gtok, gw, out);
  } else {
    router_kernel<<<N_TOKENS / 4, 256, 0, stream>>>(x, Wr, tokE, tokW, tokP, nullptr);
    hist_kernel<<<N_TOKENS / 256, 256, 0, stream>>>(tokP, tokE, meta);
    offsets_kernel<<<1, 64, 0, stream>>>(meta, out);
    scatter_kernel<<<N_TOKENS / 256, 256, 0, stream>>>(meta, tokE, tokW, gtok, gw);
    gemm1_kernel<<<dim3(HID / 128, MAXTILES), 256, 0, stream>>>(x, W1, b1, meta, gtok, h);
    gemm2_kernel<<<dim3(DIM / 128, MAXTILES), 256, 0, stream>>>(h, W2, b2, meta, gtok, gw, out);
  }
}